// Round 1
// 1407.283 us; speedup vs baseline: 1.5573x; 1.5573x over previous
//
#include <hip/hip_runtime.h>
#include <hip/hip_bf16.h>
#include <math.h>

#define T_TOK 65536
#define C_DIM 1024
#define H_DIM 512
#define Q_DIM 256

typedef __attribute__((ext_vector_type(8))) short short8;
typedef __attribute__((ext_vector_type(4))) float f32x4;
typedef unsigned int u32;
typedef unsigned short u16;

#define MFMA16(a, b, c) __builtin_amdgcn_mfma_f32_16x16x32_bf16((a), (b), (c), 0, 0, 0)

#define WS_B1H 0u
#define WS_B1L (WS_B1H + 1048576u)
#define WS_B2H (WS_B1L + 1048576u)
#define WS_B2L (WS_B2H + 524288u)
#define WS_B3H (WS_B2L + 524288u)
#define WS_B3L (WS_B3H + 262144u)
#define WS_BIAS2 (WS_B3L + 262144u)
#define WS_CNT  (WS_BIAS2 + 2048u)
#define WS_LIST (WS_CNT + 256u)
#define WS_W3   (WS_LIST + 32768u)
#define WS_NEED (WS_W3 + 1024u)

#define RC_CAP 8192
// bf16x3 split-GEMM z-error is ~3e-5 (see R1 analysis); t-error ~1e-5.
// 1e-3 guard band = ~100x margin while flagging only ~0.1% of tokens.
#define RC_EPS 1e-3f

__device__ __forceinline__ float gelu_exact(float x) {
    return 0.5f * x * (1.0f + erff(x * 0.70710678118654752440f));
}
__device__ __forceinline__ u16 bf16_rne(float f) {
    u32 u = __float_as_uint(f);
    u32 r = u + 0x7fffu + ((u >> 16) & 1u);
    return (u16)(r >> 16);
}
__device__ __forceinline__ void split_bf16(float f, u16& hi, u16& lo) {
    u16 h = bf16_rne(f);
    float hf = __uint_as_float(((u32)h) << 16);
    hi = h;
    lo = bf16_rne(f - hf);
}

// pack weights into MFMA B-fragment layout (hi/lo split); also zero recheck counter
__global__ __launch_bounds__(256) void pack_kernel(const float* __restrict__ WL,
                                                   const float* __restrict__ Wl1,
                                                   const float* __restrict__ Wl2,
                                                   const float* __restrict__ w3,
                                                   unsigned char* __restrict__ ws) {
    u16* B1h = (u16*)(ws + WS_B1H); u16* B1l = (u16*)(ws + WS_B1L);
    u16* B2h = (u16*)(ws + WS_B2H); u16* B2l = (u16*)(ws + WS_B2L);
    u16* B3h = (u16*)(ws + WS_B3H); u16* B3l = (u16*)(ws + WS_B3L);
    int gid = blockIdx.x * 256 + threadIdx.x;
    if (gid == 0) *(int*)(ws + WS_CNT) = 0;
    if (gid < 256) ((float*)(ws + WS_W3))[gid] = w3[gid];
    int lane = gid & 63;
    int tg = gid >> 6;
    int kq = lane >> 4;
    int nn = lane & 15;
    if (tg < 1024) {
        int nt = tg >> 5, kt = tg & 31;
        int n = nt * 16 + nn;
        #pragma unroll
        for (int j = 0; j < 8; ++j) {
            int k = kt * 32 + kq * 8 + j;
            u16 h, l; split_bf16(WL[(size_t)k * 512 + n], h, l);
            B1h[(size_t)tg * 512 + lane * 8 + j] = h;
            B1l[(size_t)tg * 512 + lane * 8 + j] = l;
        }
    } else if (tg < 1536) {
        int t2 = tg - 1024;
        int nt = t2 >> 4, kt = t2 & 15;
        int n = nt * 16 + nn;
        #pragma unroll
        for (int j = 0; j < 8; ++j) {
            int k = kt * 32 + kq * 8 + j;
            u16 h, l; split_bf16(Wl1[(size_t)k * 512 + n], h, l);
            B2h[(size_t)t2 * 512 + lane * 8 + j] = h;
            B2l[(size_t)t2 * 512 + lane * 8 + j] = l;
        }
    } else if (tg < 1792) {
        int t3 = tg - 1536;
        int nt = t3 >> 4, kt = t3 & 15;
        int n = nt * 16 + nn;
        #pragma unroll
        for (int j = 0; j < 8; ++j) {
            int k = kt * 32 + kq * 8 + j;
            u16 h, l; split_bf16(Wl2[(size_t)k * 256 + n], h, l);
            B3h[(size_t)t3 * 512 + lane * 8 + j] = h;
            B3l[(size_t)t3 * 512 + lane * 8 + j] = l;
        }
    }
}

__global__ void bias2_kernel(const float* __restrict__ nf,
                             const float* __restrict__ Wl1,
                             float* __restrict__ bias2) {
    int n = blockIdx.x * blockDim.x + threadIdx.x;
    if (n >= H_DIM) return;
    float s = 0.0f;
    for (int j = 0; j < H_DIM; ++j)
        s = fmaf(nf[j], Wl1[(size_t)(H_DIM + j) * H_DIM + n], s);
    bias2[n] = s;
}

#define MTOK 64
#define SA_STR 136
#define SH_STR 520
#define S3_STR 260

__global__ __launch_bounds__(512, 2)
void chanFSM_mfma_kernel(const float* __restrict__ x,
                         const float* __restrict__ prev_m,
                         const float* __restrict__ gamma,
                         const float* __restrict__ beta,
                         const unsigned char* __restrict__ ws,
                         float* __restrict__ out,
                         float* __restrict__ out_mask,
                         float* __restrict__ out_curr) {
    __shared__ __align__(16) unsigned char smem[133120];
    __shared__ float sMu[MTOK], sRs[MTOK], sFlag[MTOK];
    __shared__ float sBias[H_DIM];
    __shared__ float sw3[Q_DIM];

    u16* sAh = (u16*)smem;
    u16* sAl = sAh + MTOK * SA_STR;
    u16* sHh = (u16*)smem;
    u16* sHl = sHh + MTOK * SH_STR;
    float* sH3 = (float*)smem;

    const u16* B1h = (const u16*)(ws + WS_B1H); const u16* B1l = (const u16*)(ws + WS_B1L);
    const u16* B2h = (const u16*)(ws + WS_B2H); const u16* B2l = (const u16*)(ws + WS_B2L);
    const u16* B3h = (const u16*)(ws + WS_B3H); const u16* B3l = (const u16*)(ws + WS_B3L);
    int* rc_cnt  = (int*)(ws + WS_CNT);
    int* rc_list = (int*)(ws + WS_LIST);

    const int tid = threadIdx.x;
    const int t0  = blockIdx.x * MTOK;
    const int wid = tid >> 6;
    const int ln  = tid & 63;
    const int rg  = wid & 1;
    const int cg  = wid >> 1;
    const int lm  = ln & 15;
    const int lq  = ln >> 4;

    if (tid < H_DIM) sBias[tid] = ((const float*)(ws + WS_BIAS2))[tid];
    if (tid < Q_DIM) sw3[tid] = ((const float*)(ws + WS_W3))[tid];

    // Phase 1: LN stats
    for (int m = wid * 8; m < wid * 8 + 8; ++m) {
        const float* row = x + (size_t)(t0 + m) * C_DIM;
        double ds = 0.0, dq = 0.0;
        #pragma unroll
        for (int j = 0; j < 16; ++j) {
            float v = row[ln + (j << 6)];
            ds += (double)v; dq += (double)v * (double)v;
        }
        #pragma unroll
        for (int off = 32; off > 0; off >>= 1) {
            ds += __shfl_down(ds, off);
            dq += __shfl_down(dq, off);
        }
        if (ln == 0) {
            double mu = ds * (1.0 / 1024.0);
            double var = dq * (1.0 / 1024.0) - mu * mu;
            sMu[m] = (float)mu;
            sRs[m] = 1.0f / sqrtf((float)var + 1e-5f);
        }
    }

    // Phase 2: GEMM1 (K=1024, staged in 8 chunks of 128)
    f32x4 acc[2][8];
    #pragma unroll
    for (int rt = 0; rt < 2; ++rt)
        #pragma unroll
        for (int c = 0; c < 8; ++c) acc[rt][c] = (f32x4){0.f, 0.f, 0.f, 0.f};

    for (int chunk = 0; chunk < 8; ++chunk) {
        __syncthreads();
        #pragma unroll
        for (int i = 0; i < 4; ++i) {
            int fq = tid + (i << 9);
            int row = fq >> 5, kq = fq & 31;
            const float4 v = *(const float4*)&x[(size_t)(t0 + row) * C_DIM + chunk * 128 + kq * 4];
            float mu = sMu[row], rs = sRs[row];
            int gk = chunk * 128 + kq * 4;
            float a0 = fmaf((v.x - mu) * rs, gamma[gk],     beta[gk]);
            float a1 = fmaf((v.y - mu) * rs, gamma[gk + 1], beta[gk + 1]);
            float a2 = fmaf((v.z - mu) * rs, gamma[gk + 2], beta[gk + 2]);
            float a3 = fmaf((v.w - mu) * rs, gamma[gk + 3], beta[gk + 3]);
            u16 h0, l0, h1, l1, h2, l2, h3, l3;
            split_bf16(a0, h0, l0); split_bf16(a1, h1, l1);
            split_bf16(a2, h2, l2); split_bf16(a3, h3, l3);
            uint2 ph = make_uint2((u32)h0 | ((u32)h1 << 16), (u32)h2 | ((u32)h3 << 16));
            uint2 pl = make_uint2((u32)l0 | ((u32)l1 << 16), (u32)l2 | ((u32)l3 << 16));
            *(uint2*)&sAh[row * SA_STR + kq * 4] = ph;
            *(uint2*)&sAl[row * SA_STR + kq * 4] = pl;
        }
        __syncthreads();

        #pragma unroll
        for (int kt = 0; kt < 4; ++kt) {
            short8 ah[2], al[2];
            #pragma unroll
            for (int rt = 0; rt < 2; ++rt) {
                int row = rg * 32 + rt * 16 + lm;
                ah[rt] = *(const short8*)&sAh[row * SA_STR + kt * 32 + lq * 8];
                al[rt] = *(const short8*)&sAl[row * SA_STR + kt * 32 + lq * 8];
            }
            int ktg = chunk * 4 + kt;
            short8 bh[8], bl[8];
            #pragma unroll
            for (int c = 0; c < 8; ++c) {
                int tile = (cg * 8 + c) * 32 + ktg;
                bh[c] = *(const short8*)&B1h[(size_t)tile * 512 + ln * 8];
                bl[c] = *(const short8*)&B1l[(size_t)tile * 512 + ln * 8];
            }
            #pragma unroll
            for (int c = 0; c < 8; ++c)
                #pragma unroll
                for (int rt = 0; rt < 2; ++rt) {
                    acc[rt][c] = MFMA16(ah[rt], bh[c], acc[rt][c]);
                    acc[rt][c] = MFMA16(ah[rt], bl[c], acc[rt][c]);
                    acc[rt][c] = MFMA16(al[rt], bh[c], acc[rt][c]);
                }
        }
    }
    __syncthreads();
    #pragma unroll
    for (int rt = 0; rt < 2; ++rt)
        #pragma unroll
        for (int c = 0; c < 8; ++c) {
            int col = (cg * 8 + c) * 16 + lm;
            #pragma unroll
            for (int r = 0; r < 4; ++r) {
                int row = rg * 32 + rt * 16 + lq * 4 + r;
                u16 h, l; split_bf16(gelu_exact(acc[rt][c][r]), h, l);
                sHh[row * SH_STR + col] = h;
                sHl[row * SH_STR + col] = l;
            }
        }
    __syncthreads();

    // Phase 3: GEMM2 (K=512) + bias2
    f32x4 acc2[2][8];
    #pragma unroll
    for (int rt = 0; rt < 2; ++rt)
        #pragma unroll
        for (int c = 0; c < 8; ++c) {
            float b = sBias[(cg * 8 + c) * 16 + lm];
            acc2[rt][c] = (f32x4){b, b, b, b};
        }
    #pragma unroll 2
    for (int kt = 0; kt < 16; ++kt) {
        short8 ah[2], al[2];
        #pragma unroll
        for (int rt = 0; rt < 2; ++rt) {
            int row = rg * 32 + rt * 16 + lm;
            ah[rt] = *(const short8*)&sHh[row * SH_STR + kt * 32 + lq * 8];
            al[rt] = *(const short8*)&sHl[row * SH_STR + kt * 32 + lq * 8];
        }
        short8 bh[8], bl[8];
        #pragma unroll
        for (int c = 0; c < 8; ++c) {
            int tile = (cg * 8 + c) * 16 + kt;
            bh[c] = *(const short8*)&B2h[(size_t)tile * 512 + ln * 8];
            bl[c] = *(const short8*)&B2l[(size_t)tile * 512 + ln * 8];
        }
        #pragma unroll
        for (int c = 0; c < 8; ++c)
            #pragma unroll
            for (int rt = 0; rt < 2; ++rt) {
                acc2[rt][c] = MFMA16(ah[rt], bh[c], acc2[rt][c]);
                acc2[rt][c] = MFMA16(ah[rt], bl[c], acc2[rt][c]);
                acc2[rt][c] = MFMA16(al[rt], bh[c], acc2[rt][c]);
            }
    }
    __syncthreads();
    #pragma unroll
    for (int rt = 0; rt < 2; ++rt)
        #pragma unroll
        for (int c = 0; c < 8; ++c) {
            int col = (cg * 8 + c) * 16 + lm;
            #pragma unroll
            for (int r = 0; r < 4; ++r) {
                int row = rg * 32 + rt * 16 + lq * 4 + r;
                u16 h, l; split_bf16(gelu_exact(acc2[rt][c][r]), h, l);
                sHh[row * SH_STR + col] = h;
                sHl[row * SH_STR + col] = l;
            }
        }
    __syncthreads();

    // Phase 4: GEMM3 (K=512, N=256)
    f32x4 acc3[2][4];
    #pragma unroll
    for (int rt = 0; rt < 2; ++rt)
        #pragma unroll
        for (int c = 0; c < 4; ++c) acc3[rt][c] = (f32x4){0.f, 0.f, 0.f, 0.f};
    #pragma unroll 2
    for (int kt = 0; kt < 16; ++kt) {
        short8 ah[2], al[2];
        #pragma unroll
        for (int rt = 0; rt < 2; ++rt) {
            int row = rg * 32 + rt * 16 + lm;
            ah[rt] = *(const short8*)&sHh[row * SH_STR + kt * 32 + lq * 8];
            al[rt] = *(const short8*)&sHl[row * SH_STR + kt * 32 + lq * 8];
        }
        short8 bh[4], bl[4];
        #pragma unroll
        for (int c = 0; c < 4; ++c) {
            int tile = (cg * 4 + c) * 16 + kt;
            bh[c] = *(const short8*)&B3h[(size_t)tile * 512 + ln * 8];
            bl[c] = *(const short8*)&B3l[(size_t)tile * 512 + ln * 8];
        }
        #pragma unroll
        for (int c = 0; c < 4; ++c)
            #pragma unroll
            for (int rt = 0; rt < 2; ++rt) {
                acc3[rt][c] = MFMA16(ah[rt], bh[c], acc3[rt][c]);
                acc3[rt][c] = MFMA16(ah[rt], bl[c], acc3[rt][c]);
                acc3[rt][c] = MFMA16(al[rt], bh[c], acc3[rt][c]);
            }
    }
    __syncthreads();
    #pragma unroll
    for (int rt = 0; rt < 2; ++rt)
        #pragma unroll
        for (int c = 0; c < 4; ++c) {
            int col = (cg * 4 + c) * 16 + lm;
            #pragma unroll
            for (int r = 0; r < 4; ++r) {
                int row = rg * 32 + rt * 16 + lq * 4 + r;
                sH3[row * S3_STR + col] = gelu_exact(acc3[rt][c][r]);
            }
        }
    __syncthreads();

    // Phase 5: GEMM4 + sigmoid + STE + recheck flag
    for (int m = wid * 8; m < wid * 8 + 8; ++m) {
        float z = 0.0f;
        #pragma unroll
        for (int j = 0; j < 4; ++j) {
            int k = ln + (j << 6);
            z = fmaf(sH3[m * S3_STR + k], sw3[k], z);
        }
        #pragma unroll
        for (int off = 32; off > 0; off >>= 1) z += __shfl_down(z, off);
        if (ln == 0) {
            float prob = 1.0f / (1.0f + expf(-z));
            float t = prob * prev_m[t0 + m];
            float c = (t > 0.5f) ? 1.0f : 0.0f;
            sFlag[m] = c;
            out_mask[t0 + m] = c;
            out_curr[t0 + m] = (c > 0.0f) ? 1.0f : 1e-10f;
            if (fabsf(t - 0.5f) < RC_EPS) {
                int i = atomicAdd(rc_cnt, 1);
                if (i < RC_CAP) rc_list[i] = t0 + m;
            }
        }
    }
    __syncthreads();

    // Phase 6: out = x * curr_m
    const float4* x4 = (const float4*)(x   + (size_t)t0 * C_DIM);
    float4*       o4 = (float4*)      (out + (size_t)t0 * C_DIM);
    #pragma unroll 4
    for (int i = 0; i < 32; ++i) {
        int idx = tid + (i << 9);
        int m = idx >> 8;
        float c = sFlag[m];
        float4 v = x4[idx];
        v.x *= c; v.y *= c; v.z *= c; v.w *= c;
        o4[idx] = v;
    }
}

// fp32 exact recheck for borderline tokens — token-batched rewrite.
// 8 tokens per block, 256 threads; each thread owns 2 output columns
// (float2 coalesced weight loads) x 8 tokens (activations broadcast from
// LDS via b128 reads). Weight stream amortized 8x; 64 independent FMA
// chains per k-step hide L2/L3 latency. Every per-output accumulation
// REPLICATES THE PREVIOUS RECHECK BIT-EXACTLY: same k-mod-4 4-accumulator
// split, same (s0+s1)+(s2+s3) combine, same fp64 LN stats + shuffle tree,
// same GEMM4 reduction order. Only the thread/block assignment changed.
__global__ __launch_bounds__(256, 2)
void recheck_kernel(const float* __restrict__ x, const float* __restrict__ prev_m,
                    const float* __restrict__ gamma, const float* __restrict__ beta,
                    const float* __restrict__ WL, const float* __restrict__ Wl1,
                    const float* __restrict__ Wl2, const float* __restrict__ w3,
                    const unsigned char* __restrict__ ws,
                    float* __restrict__ out, float* __restrict__ out_mask,
                    float* __restrict__ out_curr) {
    __shared__ __align__(16) float sx[8 * 1024];
    __shared__ __align__(16) float sh1[8 * 512];
    __shared__ __align__(16) float sh2[8 * 512];
    __shared__ __align__(16) float sh3[8 * 256];
    __shared__ double srA[8][4], srB[8][4];
    __shared__ float sMu[8], sRs[8], sFlag[8];
    __shared__ int sTok[8];

    const float* bias2 = (const float*)(ws + WS_BIAS2);
    const int* cnt = (const int*)(ws + WS_CNT);
    const int* list = (const int*)(ws + WS_LIST);
    int n = *cnt; if (n > RC_CAP) n = RC_CAP;
    if (blockIdx.x * 8 >= n) return;

    const int tid = threadIdx.x, wid = tid >> 6, ln = tid & 63;

    if (tid < 8) {
        int it = blockIdx.x * 8 + tid;
        sTok[tid] = (it < n) ? list[it] : -1;
    }
    __syncthreads();

    // stage 8 token rows into LDS (raw)
    #pragma unroll
    for (int g = 0; g < 8; ++g) {
        int tk = sTok[g];
        if (tk >= 0) {
            const float* row = x + (size_t)tk * C_DIM;
            #pragma unroll
            for (int j = 0; j < 4; ++j)
                sx[g * 1024 + tid + (j << 8)] = row[tid + (j << 8)];
        } else {
            #pragma unroll
            for (int j = 0; j < 4; ++j)
                sx[g * 1024 + tid + (j << 8)] = 0.f;
        }
    }
    __syncthreads();

    // LN stats per token (bit-exact replication of previous scheme)
    #pragma unroll
    for (int g = 0; g < 8; ++g) {
        double ds = 0.0, dq = 0.0;
        #pragma unroll
        for (int j = 0; j < 4; ++j) {
            float v = sx[g * 1024 + tid + (j << 8)];
            ds += (double)v; dq += (double)v * (double)v;
        }
        #pragma unroll
        for (int off = 32; off > 0; off >>= 1) {
            ds += __shfl_down(ds, off); dq += __shfl_down(dq, off);
        }
        if (ln == 0) { srA[g][wid] = ds; srB[g][wid] = dq; }
    }
    __syncthreads();
    if (tid < 8) {
        double tds = srA[tid][0] + srA[tid][1] + srA[tid][2] + srA[tid][3];
        double tdq = srB[tid][0] + srB[tid][1] + srB[tid][2] + srB[tid][3];
        double mud = tds * (1.0 / 1024.0);
        sMu[tid] = (float)mud;
        sRs[tid] = 1.0f / sqrtf((float)(tdq * (1.0 / 1024.0) - mud * mud) + 1e-5f);
    }
    __syncthreads();
    // normalize in place
    #pragma unroll
    for (int g = 0; g < 8; ++g) {
        float mu = sMu[g], rs = sRs[g];
        #pragma unroll
        for (int j = 0; j < 4; ++j) {
            int k = tid + (j << 8);
            sx[g * 1024 + k] = fmaf((sx[g * 1024 + k] - mu) * rs, gamma[k], beta[k]);
        }
    }
    __syncthreads();

    // GEMM1: [8 tok] x (1024 -> 512), thread owns cols {2*tid, 2*tid+1}
    {
        float acc[2][8][4];
        #pragma unroll
        for (int o = 0; o < 2; ++o)
            #pragma unroll
            for (int g = 0; g < 8; ++g)
                #pragma unroll
                for (int i = 0; i < 4; ++i) acc[o][g][i] = 0.f;
        const float2* Wp = (const float2*)WL + tid;  // row stride 256 float2
        #pragma unroll 2
        for (int k = 0; k < 1024; k += 4) {
            float2 w0 = Wp[(size_t)(k + 0) * 256];
            float2 w1 = Wp[(size_t)(k + 1) * 256];
            float2 w2 = Wp[(size_t)(k + 2) * 256];
            float2 w3v = Wp[(size_t)(k + 3) * 256];
            #pragma unroll
            for (int g = 0; g < 8; ++g) {
                float4 a = *(const float4*)&sx[g * 1024 + k];
                acc[0][g][0] = fmaf(a.x, w0.x, acc[0][g][0]);
                acc[1][g][0] = fmaf(a.x, w0.y, acc[1][g][0]);
                acc[0][g][1] = fmaf(a.y, w1.x, acc[0][g][1]);
                acc[1][g][1] = fmaf(a.y, w1.y, acc[1][g][1]);
                acc[0][g][2] = fmaf(a.z, w2.x, acc[0][g][2]);
                acc[1][g][2] = fmaf(a.z, w2.y, acc[1][g][2]);
                acc[0][g][3] = fmaf(a.w, w3v.x, acc[0][g][3]);
                acc[1][g][3] = fmaf(a.w, w3v.y, acc[1][g][3]);
            }
        }
        #pragma unroll
        for (int g = 0; g < 8; ++g) {
            float o0 = (acc[0][g][0] + acc[0][g][1]) + (acc[0][g][2] + acc[0][g][3]);
            float o1 = (acc[1][g][0] + acc[1][g][1]) + (acc[1][g][2] + acc[1][g][3]);
            float2 gv; gv.x = gelu_exact(o0); gv.y = gelu_exact(o1);
            *(float2*)&sh1[g * 512 + 2 * tid] = gv;
        }
    }
    __syncthreads();

    // GEMM2: [8 tok] x (512 -> 512) + bias2 (bias seeds s0 chain, as before)
    {
        float acc[2][8][4];
        float2 b2 = ((const float2*)bias2)[tid];
        #pragma unroll
        for (int g = 0; g < 8; ++g) {
            acc[0][g][0] = b2.x; acc[1][g][0] = b2.y;
            #pragma unroll
            for (int i = 1; i < 4; ++i) { acc[0][g][i] = 0.f; acc[1][g][i] = 0.f; }
        }
        const float2* Wp = (const float2*)Wl1 + tid;  // rows 0..511, stride 256 float2
        #pragma unroll 2
        for (int k = 0; k < 512; k += 4) {
            float2 w0 = Wp[(size_t)(k + 0) * 256];
            float2 w1 = Wp[(size_t)(k + 1) * 256];
            float2 w2 = Wp[(size_t)(k + 2) * 256];
            float2 w3v = Wp[(size_t)(k + 3) * 256];
            #pragma unroll
            for (int g = 0; g < 8; ++g) {
                float4 a = *(const float4*)&sh1[g * 512 + k];
                acc[0][g][0] = fmaf(a.x, w0.x, acc[0][g][0]);
                acc[1][g][0] = fmaf(a.x, w0.y, acc[1][g][0]);
                acc[0][g][1] = fmaf(a.y, w1.x, acc[0][g][1]);
                acc[1][g][1] = fmaf(a.y, w1.y, acc[1][g][1]);
                acc[0][g][2] = fmaf(a.z, w2.x, acc[0][g][2]);
                acc[1][g][2] = fmaf(a.z, w2.y, acc[1][g][2]);
                acc[0][g][3] = fmaf(a.w, w3v.x, acc[0][g][3]);
                acc[1][g][3] = fmaf(a.w, w3v.y, acc[1][g][3]);
            }
        }
        #pragma unroll
        for (int g = 0; g < 8; ++g) {
            float o0 = (acc[0][g][0] + acc[0][g][1]) + (acc[0][g][2] + acc[0][g][3]);
            float o1 = (acc[1][g][0] + acc[1][g][1]) + (acc[1][g][2] + acc[1][g][3]);
            float2 gv; gv.x = gelu_exact(o0); gv.y = gelu_exact(o1);
            *(float2*)&sh2[g * 512 + 2 * tid] = gv;
        }
    }
    __syncthreads();

    // GEMM3: [8 tok] x (512 -> 256), thread owns col tid
    {
        float acc[8][4];
        #pragma unroll
        for (int g = 0; g < 8; ++g)
            #pragma unroll
            for (int i = 0; i < 4; ++i) acc[g][i] = 0.f;
        const float* Wp = Wl2 + tid;  // row stride 256
        #pragma unroll 2
        for (int k = 0; k < 512; k += 4) {
            float w0 = Wp[(size_t)(k + 0) * 256];
            float w1 = Wp[(size_t)(k + 1) * 256];
            float w2 = Wp[(size_t)(k + 2) * 256];
            float w3v = Wp[(size_t)(k + 3) * 256];
            #pragma unroll
            for (int g = 0; g < 8; ++g) {
                float4 a = *(const float4*)&sh2[g * 512 + k];
                acc[g][0] = fmaf(a.x, w0, acc[g][0]);
                acc[g][1] = fmaf(a.y, w1, acc[g][1]);
                acc[g][2] = fmaf(a.z, w2, acc[g][2]);
                acc[g][3] = fmaf(a.w, w3v, acc[g][3]);
            }
        }
        #pragma unroll
        for (int g = 0; g < 8; ++g)
            sh3[g * 256 + tid] = gelu_exact((acc[g][0] + acc[g][1]) + (acc[g][2] + acc[g][3]));
    }
    __syncthreads();

    // GEMM4: z per token (replicates previous order: per-thread product,
    // wave shuffle tree, per-wave double partial, left-assoc combine)
    {
        float zz[8];
        float wv = w3[tid];
        #pragma unroll
        for (int g = 0; g < 8; ++g) zz[g] = sh3[g * 256 + tid] * wv;
        #pragma unroll
        for (int off = 32; off > 0; off >>= 1) {
            #pragma unroll
            for (int g = 0; g < 8; ++g) zz[g] += __shfl_down(zz[g], off);
        }
        if (ln == 0) {
            #pragma unroll
            for (int g = 0; g < 8; ++g) srA[g][wid] = (double)zz[g];
        }
    }
    __syncthreads();
    if (tid < 8) {
        int tk = sTok[tid];
        if (tk >= 0) {
            float z = (float)(srA[tid][0] + srA[tid][1] + srA[tid][2] + srA[tid][3]);
            float prob = 1.0f / (1.0f + expf(-z));
            float t = prob * prev_m[tk];
            float c = (t > 0.5f) ? 1.0f : 0.0f;
            out_mask[tk] = c;
            out_curr[tk] = (c > 0.0f) ? 1.0f : 1e-10f;
            sFlag[tid] = c;
        }
    }
    __syncthreads();
    #pragma unroll
    for (int g = 0; g < 8; ++g) {
        int tk = sTok[g];
        if (tk < 0) continue;
        float c = sFlag[g];
        float4 v = ((const float4*)(x + (size_t)tk * C_DIM))[tid];
        v.x *= c; v.y *= c; v.z *= c; v.w *= c;
        ((float4*)(out + (size_t)tk * C_DIM))[tid] = v;
    }
}

extern "C" void kernel_launch(void* const* d_in, const int* in_sizes, int n_in,
                              void* d_out, int out_size, void* d_ws, size_t ws_size,
                              hipStream_t stream) {
    const float* x      = (const float*)d_in[0];
    const float* nf     = (const float*)d_in[1];
    const float* prev_m = (const float*)d_in[2];
    const float* gamma  = (const float*)d_in[3];
    const float* beta   = (const float*)d_in[4];
    const float* WL     = (const float*)d_in[5];
    const float* Wl1    = (const float*)d_in[6];
    const float* Wl2    = (const float*)d_in[7];
    const float* w3     = (const float*)d_in[8];

    float* out      = (float*)d_out;
    float* out_mask = out + (size_t)T_TOK * C_DIM;
    float* out_curr = out_mask + T_TOK;

    unsigned char* ws = (unsigned char*)d_ws;

    pack_kernel<<<448, 256, 0, stream>>>(WL, Wl1, Wl2, w3, ws);
    bias2_kernel<<<1, 512, 0, stream>>>(nf, Wl1, (float*)(ws + WS_BIAS2));

    chanFSM_mfma_kernel<<<T_TOK / MTOK, 512, 0, stream>>>(
        x, prev_m, gamma, beta, ws, out, out_mask, out_curr);

    recheck_kernel<<<RC_CAP / 8, 256, 0, stream>>>(
        x, prev_m, gamma, beta, WL, Wl1, Wl2, w3, ws, out, out_mask, out_curr);
}